// Round 4
// baseline (3296.560 us; speedup 1.0000x reference)
//
#include <hip/hip_runtime.h>
#include <hip/hip_bf16.h>
#include <math.h>

#define B_    8
#define LSEQ  256
#define U_    512
#define HH    8
#define DK_   64
#define FF_   2048
#define NVOC  32000
#define NL    6

typedef unsigned short u16;
typedef __attribute__((ext_vector_type(8))) short bf16x8;
typedef __attribute__((ext_vector_type(4))) float f32x4;

#define MFMA16(a, b, c) __builtin_amdgcn_mfma_f32_16x16x32_bf16(a, b, c, 0, 0, 0)

__device__ __forceinline__ u16 f2b(float v) {
  __hip_bfloat16 h = __float2bfloat16(v);
  return *reinterpret_cast<u16*>(&h);
}

// async global->LDS, 16B per lane. LDS dest = wave-uniform base + lane*16.
__device__ __forceinline__ void gld16(const void* g, void* l) {
  __builtin_amdgcn_global_load_lds(
      (__attribute__((address_space(1))) void*)g,
      (__attribute__((address_space(3))) void*)l, 16, 0, 0);
}

// ---------------- fp32 -> bf16 weight conversion (8 elems/thread) --------
__global__ __launch_bounds__(256) void cvt_k(const float* __restrict__ s,
                                             u16* __restrict__ d) {
  const long long i = (((long long)blockIdx.x) * 256 + threadIdx.x) * 8;
  const float4 a = *(const float4*)(s + i);
  const float4 b = *(const float4*)(s + i + 4);
  ushort4 lo, hi;
  lo.x = f2b(a.x); lo.y = f2b(a.y); lo.z = f2b(a.z); lo.w = f2b(a.w);
  hi.x = f2b(b.x); hi.y = f2b(b.y); hi.z = f2b(b.z); hi.w = f2b(b.w);
  *(ushort4*)(d + i) = lo;
  *(ushort4*)(d + i + 4) = hi;
}

// ---------------- embedding: fp32 act (b,u,l) + bf16 shadow (b,l,u) ------
__global__ __launch_bounds__(256) void embed_k(const int* __restrict__ tok,
    const float* __restrict__ emb, const float* __restrict__ pe,
    float* __restrict__ out, u16* __restrict__ shad, float scale) {
  const long long i = (long long)blockIdx.x * 256 + threadIdx.x;
  const int l = (int)(i & (LSEQ - 1));
  const long long t = i >> 8;
  const int u = (int)(t & (U_ - 1));
  const int b = (int)(t >> 9);
  const int tk = tok[b * LSEQ + l];
  const float v = emb[(long long)tk * U_ + u] * scale + pe[u * 500 + l];
  out[i] = v;
  shad[((long long)(b * LSEQ + l)) * U_ + u] = f2b(v);
}

// ---------------- MFMA bf16 GEMM ----------------------------------------
// C[m,n] = sum_k A[m,k]*B[n,k]; A rows with ldA, B rows with ldB (elements).
// Tile: (WR*64) x (WC*64), 4 waves in WR x WC grid, each wave 64x64 via
// 4x4 frags of mfma 16x16x32 (verified m89/m97 layout). z -> (bb,hh) by Hdiv.
// Staging: global_load_lds_dwordx4, linear LDS (lane's dest = 16B*tid).
// EPI 0: fp32 C[m*ldc+n]                                    [scores]
// EPI 1: fp32 C = acc+bias+R (in-place resid) + bf16 T[n*ldT+m]  [outproj/FFN2]
// EPI 2: bf16 T[n*ldT+m] = relu(acc+bias)                   [FFN1]
// EPI 3: fp32 transposed store C[n*ldc+m] via per-wave LDS   [logits]
// EPI 4: bf16 dual: C16[m*ldc+n] and T[n*ldT+m], rows m<qrows scaled 1/8 [QKV]
// EPI 5: bf16 C16[m*ldc+n]                                  [PV -> attC]
struct MArgs {
  const u16* A; const u16* B;
  float* C; u16* T; u16* C16;
  const float* bias; const float* R;
  int K, ldA, ldB, ldc, ldT, Hdiv, qrows;
  long long sAb, sAh, sBb, sBh, sCb, sCh, sTb, sTh;
};

template<int EPI, int WR, int WC>
__global__ __launch_bounds__(256) void mgemm_k(MArgs g) {
  static_assert(WR * WC == 4, "4 waves");
  __shared__ __align__(16) u16 sm[(WR + WC) * 2048];
  u16* As = sm;
  u16* Bs = sm + WR * 2048;
  const int tid = threadIdx.x;
  const int w = tid >> 6, lane = tid & 63;
  const int wr = w / WC, wc = w % WC;
  const int fr = lane & 15, fq = lane >> 4;
  const int m0 = blockIdx.y * (WR * 64), n0 = blockIdx.x * (WC * 64);
  const int z = blockIdx.z;
  const int bb = z / g.Hdiv, hh = z - bb * g.Hdiv;
  const u16* __restrict__ Ab = g.A + bb * g.sAb + hh * g.sAh + (long long)m0 * g.ldA;
  const u16* __restrict__ Bb = g.B + bb * g.sBb + hh * g.sBh + (long long)n0 * g.ldB;

  const int srow = tid >> 2;            // 0..63
  const int schunk = (tid & 3) * 8;     // bf16 elems within a 32-col k-slice
  const u16* ap = Ab + (long long)srow * g.ldA + schunk;
  const u16* bp = Bb + (long long)srow * g.ldB + schunk;
  // wave-uniform LDS staging bases (hardware adds lane*16 bytes)
  u16* Adst = As + w * 512;
  u16* Bdst = Bs + w * 512;

  f32x4 acc[4][4] = {};
  const int nk = g.K >> 5;
  for (int t = 0; t < nk; ++t) {
    #pragma unroll
    for (int r = 0; r < WR; r++)
      gld16(ap + (long long)r * 64 * g.ldA, Adst + r * 2048);
    #pragma unroll
    for (int r = 0; r < WC; r++)
      gld16(bp + (long long)r * 64 * g.ldB, Bdst + r * 2048);
    ap += 32; bp += 32;
    __syncthreads();                    // drains vmcnt(0): tiles resident
    bf16x8 af[4], bfv[4];
    #pragma unroll
    for (int mf = 0; mf < 4; mf++)
      af[mf] = *(const bf16x8*)(const void*)&As[(wr * 64 + mf * 16 + fr) * 32 + fq * 8];
    #pragma unroll
    for (int nf = 0; nf < 4; nf++)
      bfv[nf] = *(const bf16x8*)(const void*)&Bs[(wc * 64 + nf * 16 + fr) * 32 + fq * 8];
    #pragma unroll
    for (int mf = 0; mf < 4; mf++)
      #pragma unroll
      for (int nf = 0; nf < 4; nf++)
        acc[mf][nf] = MFMA16(af[mf], bfv[nf], acc[mf][nf]);
    __syncthreads();
  }

  const int mb = m0 + wr * 64, nb = n0 + wc * 64;
  if constexpr (EPI == 0) {
    float* Cz = g.C + bb * g.sCb + hh * g.sCh;
    #pragma unroll
    for (int mf = 0; mf < 4; mf++)
      #pragma unroll
      for (int j = 0; j < 4; j++) {
        const int m = mb + mf * 16 + fq * 4 + j;
        float* cr = Cz + (long long)m * g.ldc + nb + fr;
        #pragma unroll
        for (int nf = 0; nf < 4; nf++) cr[nf * 16] = acc[mf][nf][j];
      }
  } else if constexpr (EPI == 1 || EPI == 2) {
    float* Cz = g.C ? (g.C + bb * g.sCb + hh * g.sCh) : nullptr;
    const float* Rz = g.R ? (g.R + bb * g.sCb + hh * g.sCh) : nullptr;
    u16* Tz = g.T + bb * g.sTb + hh * g.sTh;
    #pragma unroll
    for (int mf = 0; mf < 4; mf++)
      #pragma unroll
      for (int j = 0; j < 4; j++) {
        const int m = mb + mf * 16 + fq * 4 + j;
        const float bv = g.bias ? g.bias[m] : 0.f;
        #pragma unroll
        for (int nf = 0; nf < 4; nf++) {
          const int n = nb + nf * 16 + fr;
          float v = acc[mf][nf][j] + bv;
          if constexpr (EPI == 2) v = fmaxf(v, 0.f);
          if constexpr (EPI == 1) {
            const long long ci = (long long)m * g.ldc + n;
            v += Rz[ci];
            Cz[ci] = v;
          }
          Tz[(long long)n * g.ldT + m] = f2b(v);
        }
      }
  } else if constexpr (EPI == 3) {      // transposed fp32 store via LDS
    float* tr = (float*)(void*)sm + w * 1024;       // per-wave [64][16]
    float* Cz = g.C + bb * g.sCb + hh * g.sCh;
    #pragma unroll
    for (int p = 0; p < 4; p++) {
      #pragma unroll
      for (int nf = 0; nf < 4; nf++)
        #pragma unroll
        for (int j = 0; j < 4; j++)
          tr[(nf * 16 + fr) * 16 + fq * 4 + j] = acc[p][nf][j];
      // same-wave LDS ops retire in order; compiler inserts lgkmcnt waits
      #pragma unroll
      for (int r4 = 0; r4 < 4; r4++) {
        const int row = r4 * 16 + (lane >> 2);
        const int c4 = (lane & 3) * 4;
        const float4 v = *(const float4*)&tr[row * 16 + c4];
        const long long n = nb + row;                // seq position
        const long long m = mb + p * 16 + c4;        // vocab index
        *(float4*)&Cz[n * g.ldc + m] = v;
      }
    }
  } else if constexpr (EPI == 4) {      // bf16 dual orientation (QKV)
    u16* Cz = g.C16 + bb * g.sCb + hh * g.sCh;
    u16* Tz = g.T + bb * g.sTb + hh * g.sTh;
    #pragma unroll
    for (int mf = 0; mf < 4; mf++)
      #pragma unroll
      for (int j = 0; j < 4; j++) {
        const int m = mb + mf * 16 + fq * 4 + j;
        const float qs = (m < g.qrows) ? 0.125f : 1.f;
        #pragma unroll
        for (int nf = 0; nf < 4; nf++) {
          const int n = nb + nf * 16 + fr;
          const u16 hv = f2b(acc[mf][nf][j] * qs);
          Cz[(long long)m * g.ldc + n] = hv;
          Tz[(long long)n * g.ldT + m] = hv;
        }
      }
  } else {                              // EPI 5: bf16 C-orient (PV)
    u16* Cz = g.C16 + bb * g.sCb + hh * g.sCh;
    #pragma unroll
    for (int mf = 0; mf < 4; mf++)
      #pragma unroll
      for (int j = 0; j < 4; j++) {
        const int m = mb + mf * 16 + fq * 4 + j;
        #pragma unroll
        for (int nf = 0; nf < 4; nf++) {
          const int n = nb + nf * 16 + fr;
          Cz[(long long)m * g.ldc + n] = f2b(acc[mf][nf][j]);
        }
      }
  }
}

// ---------------- masked softmax: fp32 scores -> bf16 P ------------------
// mode 0: enc self (xp[q]&xp[k]); 1: dec self (+causal); 2: cross (yp&xp)
__global__ __launch_bounds__(256) void softmax_k(const float* __restrict__ S,
    u16* __restrict__ P, const int* __restrict__ xt, const int* __restrict__ yt,
    int mode) {
  const int gw   = blockIdx.x * 4 + (threadIdx.x >> 6);  // one wave per row
  const int lane = threadIdx.x & 63;
  const int q  = gw & (LSEQ - 1);
  const int bh = gw >> 8;
  const int b  = bh >> 3;
  const float* __restrict__ row = S + (long long)gw * LSEQ;
  u16* __restrict__ prow = P + (long long)gw * LSEQ;

  const bool qv = (mode == 0) ? (xt[b * LSEQ + q] != 0) : (yt[b * LSEQ + q] != 0);
  float vals[4];
  bool anyloc = false;
  float mx = -INFINITY;
  #pragma unroll
  for (int j = 0; j < 4; j++) {
    const int k = j * 64 + lane;
    bool kv;
    if (mode == 1) kv = (yt[b * LSEQ + k] != 0) && (k <= q);
    else           kv = (xt[b * LSEQ + k] != 0);
    kv = kv && qv;
    anyloc |= kv;
    vals[j] = kv ? row[k] : -1e30f;
    mx = fmaxf(mx, vals[j]);
  }
  #pragma unroll
  for (int off = 32; off >= 1; off >>= 1) mx = fmaxf(mx, __shfl_xor(mx, off));
  const bool anyrow = (__ballot(anyloc) != 0ull);
  float sum = 0.f;
  #pragma unroll
  for (int j = 0; j < 4; j++) { vals[j] = expf(vals[j] - mx); sum += vals[j]; }
  #pragma unroll
  for (int off = 32; off >= 1; off >>= 1) sum += __shfl_xor(sum, off);
  const float inv = anyrow ? (1.f / sum) : 0.f;
  #pragma unroll
  for (int j = 0; j < 4; j++) prow[j * 64 + lane] = f2b(vals[j] * inv);
}

// ---------------- fp32 VALU GEMM (only for tiny-ws logits fallback) ------
struct GemmArgs {
  const float* A; const float* B; float* C;
  int K, lda, ldb, ldc;
  long long sAb, sCb;
};

__global__ __launch_bounds__(256) void gemm_tt_k(GemmArgs g) {
  __shared__ __align__(16) float As[16][68];
  __shared__ __align__(16) float Bs[16][68];
  const int bb = blockIdx.z;
  const float* __restrict__ Ab = g.A + bb * g.sAb;
  const int m0 = blockIdx.y * 64, n0 = blockIdx.x * 64;
  const int tid = threadIdx.x;
  const int tx = tid & 15, ty = tid >> 4;
  float acc[4][4] = {};
  for (int k0 = 0; k0 < g.K; k0 += 16) {
    {
      const int mm = tid & 63, kk = tid >> 6;
      #pragma unroll
      for (int i = 0; i < 4; i++)
        As[kk + i * 4][mm] = Ab[(long long)(k0 + kk + i * 4) * g.lda + (m0 + mm)];
    }
    {
      const int kk = tid & 15, nn = tid >> 4;
      #pragma unroll
      for (int i = 0; i < 4; i++)
        Bs[kk][nn + i * 16] = g.B[(long long)(n0 + nn + i * 16) * g.ldb + (k0 + kk)];
    }
    __syncthreads();
    #pragma unroll
    for (int kk = 0; kk < 16; kk++) {
      const float4 a4 = *(const float4*)&As[kk][ty * 4];
      const float4 b4 = *(const float4*)&Bs[kk][tx * 4];
      const float av[4] = {a4.x, a4.y, a4.z, a4.w};
      const float bv[4] = {b4.x, b4.y, b4.z, b4.w};
      #pragma unroll
      for (int i = 0; i < 4; i++)
        #pragma unroll
        for (int j = 0; j < 4; j++)
          acc[i][j] += av[i] * bv[j];
    }
    __syncthreads();
  }
  float* Cb = g.C + bb * g.sCb;
  #pragma unroll
  for (int i = 0; i < 4; i++) {
    const int m = m0 + ty * 4 + i;
    float4 r;
    r.x = acc[i][0]; r.y = acc[i][1]; r.z = acc[i][2]; r.w = acc[i][3];
    *(float4*)&Cb[(long long)m * g.ldc + n0 + tx * 4] = r;
  }
}

// ---------------- driver --------------------------------------------------
extern "C" void kernel_launch(void* const* d_in, const int* in_sizes, int n_in,
                              void* d_out, int out_size, void* d_ws, size_t ws_size,
                              hipStream_t stream) {
  const int*   x    = (const int*)d_in[0];
  const int*   y    = (const int*)d_in[1];
  const float* embx = (const float*)d_in[2];
  const float* emby = (const float*)d_in[3];
  const float* pe   = (const float*)d_in[4];
  const float* encA = (const float*)d_in[5];
  const float* encW1= (const float*)d_in[6];
  const float* encB1= (const float*)d_in[7];
  const float* encW2= (const float*)d_in[8];
  const float* encB2= (const float*)d_in[9];
  const float* decS = (const float*)d_in[10];
  const float* decC = (const float*)d_in[11];
  const float* decW1= (const float*)d_in[12];
  const float* decB1= (const float*)d_in[13];
  const float* decW2= (const float*)d_in[14];
  const float* decB2= (const float*)d_in[15];
  const float* aff  = (const float*)d_in[16];
  float* out = (float*)d_out;

  const long long nAttW = (long long)NL * 4 * U_ * U_;        // 6,291,456
  const long long nAff  = (long long)NVOC * U_;               // 16,384,000
  const long long nAct  = (long long)B_ * U_ * LSEQ;          // 1,048,576
  const long long nQKV  = (long long)B_ * 3 * U_ * LSEQ;      // 3,145,728
  const long long nScor = (long long)B_ * HH * LSEQ * LSEQ;   // 4,194,304
  const long long nHid  = (long long)B_ * LSEQ * FF_;         // 4,194,304

  const size_t bW    = (size_t)nAttW * 2;         // one weight tensor, bf16
  const size_t bAff  = (size_t)nAff * 2;
  const size_t bActF = (size_t)nAct * 4;
  const size_t bShad = (size_t)nAct * 2;
  const size_t bQkv  = (size_t)nQKV * 2;          // bf16
  const size_t bScor = (size_t)nScor * 4;
  const size_t bP    = (size_t)nScor * 2;
  const size_t bHid  = (size_t)nHid * 2;
  const size_t needA = 7 * bW + bAff + 2 * bActF + 2 * bShad + 2 * bQkv +
                       bScor + bP + bShad + bHid;
  const size_t needC = bAff + 2 * bActF + 2 * bShad;

  u16 *wEncA, *wEncW1, *wEncW2, *wDecS, *wDecC, *wDecW1, *wDecW2, *wAff = nullptr;
  float *e_f, *d_f, *scor;
  u16 *es, *dsS, *qkvC, *qkvT, *pbf, *attC, *hid;

  if (ws_size >= needA) {
    char* c = (char*)d_ws;
    wEncA = (u16*)c;  c += bW;
    wEncW1= (u16*)c;  c += bW;
    wEncW2= (u16*)c;  c += bW;
    wDecS = (u16*)c;  c += bW;
    wDecC = (u16*)c;  c += bW;
    wDecW1= (u16*)c;  c += bW;
    wDecW2= (u16*)c;  c += bW;
    wAff  = (u16*)c;  c += bAff;
    e_f   = (float*)c; c += bActF;
    d_f   = (float*)c; c += bActF;
    es    = (u16*)c;  c += bShad;
    dsS   = (u16*)c;  c += bShad;
    qkvC  = (u16*)c;  c += bQkv;
    qkvT  = (u16*)c;  c += bQkv;
    scor  = (float*)c; c += bScor;
    pbf   = (u16*)c;  c += bP;
    attC  = (u16*)c;  c += bShad;
    hid   = (u16*)c;
  } else {
    // transients in d_out (all dead before the logits GEMM, which reads only
    // wAff/dsS (or d_f/aff) and then overwrites all of d_out)
    char* c = (char*)d_out;
    wEncA = (u16*)c;  c += bW;
    wEncW1= (u16*)c;  c += bW;
    wEncW2= (u16*)c;  c += bW;
    wDecS = (u16*)c;  c += bW;
    wDecC = (u16*)c;  c += bW;
    wDecW1= (u16*)c;  c += bW;
    wDecW2= (u16*)c;  c += bW;
    qkvC  = (u16*)c;  c += bQkv;
    qkvT  = (u16*)c;  c += bQkv;
    scor  = (float*)c; c += bScor;
    pbf   = (u16*)c;  c += bP;
    attC  = (u16*)c;  c += bShad;
    hid   = (u16*)c;
    char* w = (char*)d_ws;
    if (ws_size >= needC) { wAff = (u16*)w; w += bAff; }   // else fp32 logits
    e_f = (float*)w; w += bActF;
    d_f = (float*)w; w += bActF;
    es  = (u16*)w;  w += bShad;
    dsS = (u16*)w;
  }

  // ---- weight conversion (every call; buffers are re-poisoned) ----
  auto cvt = [&](const float* s, u16* d, long long n) {
    cvt_k<<<dim3((unsigned)(n / 2048)), 256, 0, stream>>>(s, d);
  };
  cvt(encA, wEncA, nAttW);  cvt(encW1, wEncW1, nAttW); cvt(encW2, wEncW2, nAttW);
  cvt(decS, wDecS, nAttW);  cvt(decC, wDecC, nAttW);
  cvt(decW1, wDecW1, nAttW);cvt(decW2, wDecW2, nAttW);
  if (wAff) cvt(aff, wAff, nAff);

  const float escale = 22.62741699796952f;  // sqrt(512)
  embed_k<<<4096, 256, 0, stream>>>(x, embx, pe, e_f, es, escale);
  embed_k<<<4096, 256, 0, stream>>>(y, emby, pe, d_f, dsS, escale);

  const long long sShad = (long long)LSEQ * U_;        // 131072
  const long long s3UL  = 3LL * U_ * LSEQ;             // 393216 (qkvC & qkvT)
  const long long sScB  = (long long)HH * LSEQ * LSEQ; // 524288
  const long long sScH  = (long long)LSEQ * LSEQ;      // 65536
  const long long sHidB = (long long)LSEQ * FF_;       // 524288

  // QKV-style projection: bf16 dual-orientation output. rows<qrows scaled 1/8.
  auto proj = [&](const u16* W, const u16* Bsh, u16* c16, u16* tT,
                  int M, int qrows) {
    MArgs a{W, Bsh, nullptr, tT, c16, nullptr, nullptr,
            U_, U_, U_, LSEQ, 3 * U_, 1, qrows,
            0, 0, sShad, 0, s3UL, 0, s3UL, 0};
    mgemm_k<4, 2, 2><<<dim3(2, M / 128, B_), 256, 0, stream>>>(a);
  };

  // full attention core, all-MFMA
  auto attn_core = [&](int mode) {
    // scores[q,k] = sum_d (Q/8)[q,d] * K[k,d]   (per b,h; Q,K from qkvT)
    MArgs s{qkvT, qkvT + 512, scor, nullptr, nullptr, nullptr, nullptr,
            DK_, 3 * U_, 3 * U_, LSEQ, 0, HH, 0,
            s3UL, DK_, s3UL, DK_, sScB, sScH, 0, 0};
    mgemm_k<0, 2, 2><<<dim3(2, 2, B_ * HH), 256, 0, stream>>>(s);
    softmax_k<<<4096, 256, 0, stream>>>(scor, pbf, x, y, mode);
    // attC[l, h*64+d] = sum_k P[q,k] * V[d,k]   (V from qkvC rows 1024+)
    MArgs p{pbf, qkvC + 1024LL * LSEQ, nullptr, nullptr, attC, nullptr, nullptr,
            LSEQ, LSEQ, LSEQ, U_, 0, HH, 0,
            sScB, sScH, s3UL, (long long)DK_ * LSEQ, sShad, DK_, 0, 0};
    mgemm_k<5, 4, 1><<<dim3(1, 1, B_ * HH), 256, 0, stream>>>(p);
  };

  // out-projection / FFN2: fp32 C += resid, bf16 shadow T
  auto projout = [&](const u16* W, const u16* Bsh, float* act, u16* shad,
                     const float* bias, int K, int ldB, long long sB) {
    MArgs a{W, Bsh, act, shad, nullptr, bias, act,
            K, K, ldB, LSEQ, U_, 1, 0,
            0, 0, sB, 0, sShad, 0, sShad, 0};
    mgemm_k<1, 2, 2><<<dim3(2, 4, B_), 256, 0, stream>>>(a);
  };

  auto ffn1 = [&](const u16* W, const u16* Bsh, const float* bias) {
    MArgs a{W, Bsh, nullptr, hid, nullptr, bias, nullptr,
            U_, U_, U_, 0, FF_, 1, 0,
            0, 0, sShad, 0, 0, 0, sHidB, 0};
    mgemm_k<2, 2, 2><<<dim3(2, 16, B_), 256, 0, stream>>>(a);
  };

  // ---- encoder ----
  for (int i = 0; i < NL; i++) {
    const u16* W = wEncA + (long long)i * 4 * U_ * U_;
    proj(W, es, qkvC, qkvT, 3 * U_, 512);
    attn_core(0);
    projout(W + 3LL * U_ * U_, attC, e_f, es, nullptr, U_, U_, sShad);
    ffn1(wEncW1 + (long long)i * FF_ * U_, es, encB1 + (long long)i * FF_);
    projout(wEncW2 + (long long)i * U_ * FF_, hid, e_f, es,
            encB2 + (long long)i * U_, FF_, FF_, sHidB);
  }

  // ---- decoder ----
  for (int i = 0; i < NL; i++) {
    const u16* Ws = wDecS + (long long)i * 4 * U_ * U_;
    proj(Ws, dsS, qkvC, qkvT, 3 * U_, 512);
    attn_core(1);
    projout(Ws + 3LL * U_ * U_, attC, d_f, dsS, nullptr, U_, U_, sShad);

    const u16* Wc = wDecC + (long long)i * 4 * U_ * U_;
    proj(Wc, dsS, qkvC, qkvT, U_, 512);                       // Q from decoder
    proj(Wc + (long long)U_ * U_, es, qkvC + 512LL * LSEQ, qkvT + 512,
         2 * U_, 0);                                           // K,V from encoder
    attn_core(2);
    projout(Wc + 3LL * U_ * U_, attC, d_f, dsS, nullptr, U_, U_, sShad);

    ffn1(wDecW1 + (long long)i * FF_ * U_, dsS, decB1 + (long long)i * FF_);
    projout(wDecW2 + (long long)i * U_ * FF_, hid, d_f, dsS,
            decB2 + (long long)i * U_, FF_, FF_, sHidB);
  }

  // ---- logits: out[b,l,v] = sum_u dsS[b,l,u] * aff[v,u] ----
  if (wAff) {
    MArgs a{wAff, dsS, out, nullptr, nullptr, nullptr, nullptr,
            U_, U_, U_, NVOC, 0, 1, 0,
            0, 0, sShad, 0, (long long)LSEQ * NVOC, 0, 0, 0};
    mgemm_k<3, 2, 2><<<dim3(2, NVOC / 128, B_), 256, 0, stream>>>(a);
  } else {
    GemmArgs a{d_f, aff, out, U_, LSEQ, U_, NVOC,
               (long long)U_ * LSEQ, (long long)LSEQ * NVOC};
    gemm_tt_k<<<dim3(NVOC / 64, 4, B_), 256, 0, stream>>>(a);
  }
}